// Round 1
// baseline (357.997 us; speedup 1.0000x reference)
//
#include <hip/hip_runtime.h>

// ---------------------------------------------------------------------------
// VM-LSTM cell, B=8192, D=H=1024, G=2, WR=64, URANKS=[64,64]
//
// Decomposition:
//   prep : build fp16 transposed stage-1 weights (Uxt, Uht[4]), fused stage-2
//          weight W2 (2 halves x 2048 x 192, fp16), and per-gate correction
//          vectors cx/ch/bb (4x1024 fp32).
//   s1   : Ta[b,0:192] = [x@Ux | h(:512)@Uh0g0 | h(512:)@Uh1g0]
//          Tb[b,0:192] = [x@Ux | h(512:)@Uh0g1 | h(:512)@Uh1g1]   (fp16, MFMA)
//   s2   : pre[q,k] = Ta/Tb @ W2 + x*cx + h*ch + bb ; LSTM elementwise ->
//          h_next, c_next.
// Gate order q: 0=i,1=f (half A, uses Ta), 2=o,3=n (half B, uses Tb).
//   jx(q) = q (gx column block), jh(q) = q^1 (gh column block).
// ---------------------------------------------------------------------------

typedef _Float16 half8 __attribute__((ext_vector_type(8)));
typedef _Float16 half4v __attribute__((ext_vector_type(4)));
typedef float f32x4 __attribute__((ext_vector_type(4)));

#define NB 8192
#define NH 1024

// workspace offsets (bytes)
#define WS_TA   0                      // 8192*192 fp16 = 3145728
#define WS_TB   3145728
#define WS_UXT  6291456                // 64*1024 fp16 = 131072
#define WS_UHT  6422528                // 4*64*512 fp16 = 262144
#define WS_W2   6684672                // 2*2048*192 fp16 = 1572864
#define WS_CX   8257536                // 4096 fp32
#define WS_CH   8273920
#define WS_BB   8290304

// ---------------------------------------------------------------------------
__global__ __launch_bounds__(256) void prep_kernel(
    const float* __restrict__ Ux, const float* __restrict__ Vx,
    const float* __restrict__ Uh0, const float* __restrict__ Vh0,
    const float* __restrict__ Uh1, const float* __restrict__ Vh1,
    const float* __restrict__ dia_x, const float* __restrict__ dia_h,
    const float* __restrict__ bias_x, const float* __restrict__ bias_h,
    _Float16* __restrict__ Uxt, _Float16* __restrict__ Uht,
    _Float16* __restrict__ W2, float* __restrict__ cx,
    float* __restrict__ ch, float* __restrict__ bb)
{
    int e = blockIdx.x * 256 + threadIdx.x;
    if (e < 65536) {
        // Uxt[r][d] = Ux[d][r], stride 1024
        int r = e >> 10, d = e & 1023;
        Uxt[e] = (_Float16)Ux[d * 64 + r];
    } else if (e < 65536 + 131072) {
        // Uht[j][r][n], j: 0=Uh0g0, 1=Uh1g0, 2=Uh0g1, 3=Uh1g1, stride 512
        int t = e - 65536;
        int j = t >> 15; int rem = t & 32767; int r = rem >> 9; int n = rem & 511;
        const float* src = (j == 0 || j == 2) ? Uh0 : Uh1;
        int g = (j >= 2) ? 1 : 0;
        Uht[t] = (_Float16)src[(g * 512 + n) * 64 + r];
    } else if (e < 983040) {
        // W2[s][v][kk]: s=0 gates (i,f), s=1 gates (o,n); v = q*1024+k; kk in [0,192)
        int t = e - 196608;
        int s = t / 393216; int rem = t - s * 393216;
        int v = rem / 192;  int kk = rem - v * 192;
        int q = v >> 10; int k = v & 1023;
        int r = kk & 63; int sect = kk >> 6;
        int jx = s * 2 + q;
        int m = (q == 0) ? (1024 + k) : k;     // column inside Vh group
        float val;
        if (sect == 0)      val = Vx[(jx * 1024 + k) * 64 + r];
        else if (sect == 1) val = Vh0[(s * 64 + r) * 2048 + m];
        else                val = Vh1[(s * 64 + r) * 2048 + m];
        W2[t] = (_Float16)val;
    } else if (e < 987136) {
        // correction vectors, q in {0:i,1:f,2:o,3:n}
        int t = e - 983040; int q = t >> 10; int k = t & 1023;
        int jh = q ^ 1;
        int fh = jh * 1024 + k; int g = fh >> 11; int m = fh & 2047;
        float sx = 0.f, sh = 0.f;
        for (int r = 0; r < 64; ++r) {
            sx += Ux[k * 64 + r] * Vx[(q * 1024 + k) * 64 + r];
            sh += Uh0[k * 64 + r] * Vh0[(g * 64 + r) * 2048 + m];
        }
        cx[t] = dia_x[k] - sx;
        ch[t] = dia_h[k] - sh;
        bb[t] = bias_x[q * 1024 + k] + bias_h[jh * 1024 + k];
    }
}

// ---------------------------------------------------------------------------
// Stage 1: 64-row x 128-col tiles, MFMA 16x16x32 f16.
// job0: A=x (K=1024), both col-groups = Uxt -> Ta[0:64] and Tb[0:64]
// job1: A=h[:, 0:512]   -> Ta[64:128] (Uht0) and Tb[128:192] (Uht3)
// job2: A=h[:,512:1024] -> Ta[128:192] (Uht1) and Tb[64:128]  (Uht2)
__global__ __launch_bounds__(256) void s1_kernel(
    const float* __restrict__ x, const float* __restrict__ h,
    const _Float16* __restrict__ Uxt, const _Float16* __restrict__ Uht,
    _Float16* __restrict__ Ta, _Float16* __restrict__ Tb)
{
    __shared__ __align__(16) _Float16 Ash[64][72];
    __shared__ __align__(16) _Float16 Bsh[128][72];

    const int job = blockIdx.y;
    const int b0 = blockIdx.x * 64;
    const int tid = threadIdx.x;
    const int w = tid >> 6, l = tid & 63, l15 = l & 15, quad = l >> 4;

    const float* src; int koff, K;
    const _Float16 *Wa, *Wb; int colA, colB;
    if (job == 0)      { src = x; koff = 0;   K = 1024; Wa = Uxt;             Wb = Uxt;             colA = 0;   colB = 0;  }
    else if (job == 1) { src = h; koff = 0;   K = 512;  Wa = Uht;             Wb = Uht + 3 * 32768; colA = 64;  colB = 128; }
    else               { src = h; koff = 512; K = 512;  Wa = Uht + 32768;     Wb = Uht + 2 * 32768; colA = 128; colB = 64; }

    f32x4 acc[8] = {};
    const int nkb = K >> 6;
    for (int kb = 0; kb < nkb; ++kb) {
        // stage A tile: 64 rows x 64 k, fp32 -> fp16
        #pragma unroll
        for (int ii = 0; ii < 4; ++ii) {
            int idx = tid + ii * 256;           // 0..1023 float4 chunks
            int row = idx >> 4, c4 = idx & 15;
            float4 f = *(const float4*)&src[(size_t)(b0 + row) * 1024 + koff + kb * 64 + c4 * 4];
            half4v p;
            p[0] = (_Float16)f.x; p[1] = (_Float16)f.y;
            p[2] = (_Float16)f.z; p[3] = (_Float16)f.w;
            *(half4v*)&Ash[row][c4 * 4] = p;
        }
        // stage B tile: 128 n-rows x 64 k (fp16)
        #pragma unroll
        for (int ii = 0; ii < 4; ++ii) {
            int idx = tid + ii * 256;           // 0..1023 8-half chunks
            int n = idx >> 3, c8 = idx & 7;
            const _Float16* Wp = (n < 64) ? (Wa + (size_t)n * K) : (Wb + (size_t)(n - 64) * K);
            *(half8*)&Bsh[n][c8 * 8] = *(const half8*)&Wp[kb * 64 + c8 * 8];
        }
        __syncthreads();
        #pragma unroll
        for (int kk0 = 0; kk0 < 64; kk0 += 32) {
            half8 a = *(const half8*)&Ash[w * 16 + l15][kk0 + quad * 8];
            #pragma unroll
            for (int nt = 0; nt < 8; ++nt) {
                half8 b = *(const half8*)&Bsh[nt * 16 + l15][kk0 + quad * 8];
                acc[nt] = __builtin_amdgcn_mfma_f32_16x16x32_f16(a, b, acc[nt], 0, 0, 0);
            }
        }
        __syncthreads();
    }
    // epilogue: D row = 4*quad + r, col = l15
    #pragma unroll
    for (int nt = 0; nt < 8; ++nt) {
        _Float16* dst = (nt < 4) ? Ta : Tb;
        int col = ((nt < 4) ? colA : colB) + (nt & 3) * 16 + l15;
        #pragma unroll
        for (int r = 0; r < 4; ++r) {
            int row = b0 + w * 16 + quad * 4 + r;
            dst[(size_t)row * 192 + col] = (_Float16)acc[nt][r];
        }
    }
}

// ---------------------------------------------------------------------------
// Stage 2: tile = 64 rows x 64 k-range; each k gets all 4 gates.
// half A (Ta, W2[0]): gates i (v=k) and f (v=1024+k), K=192
// half B (Tb, W2[1]): gates o (v=k) and n (v=1024+k), K=192
__global__ __launch_bounds__(256) void s2_kernel(
    const _Float16* __restrict__ Ta, const _Float16* __restrict__ Tb,
    const _Float16* __restrict__ W2,
    const float* __restrict__ cx, const float* __restrict__ ch,
    const float* __restrict__ bb,
    const float* __restrict__ x, const float* __restrict__ h,
    const float* __restrict__ c, float* __restrict__ out)
{
    __shared__ __align__(16) _Float16 TaSh[64][200];
    __shared__ __align__(16) _Float16 TbSh[64][200];

    const int b0 = blockIdx.x * 64;
    const int kr = blockIdx.y * 64;
    const int tid = threadIdx.x;
    const int w = tid >> 6, l = tid & 63, l15 = l & 15, quad = l >> 4;

    // stage Ta/Tb rows (full K=192)
    #pragma unroll
    for (int ii = 0; ii < 6; ++ii) {
        int idx = tid + ii * 256;               // 0..1535
        int row = idx / 24, c8 = idx % 24;
        *(half8*)&TaSh[row][c8 * 8] = *(const half8*)&Ta[(size_t)(b0 + row) * 192 + c8 * 8];
        *(half8*)&TbSh[row][c8 * 8] = *(const half8*)&Tb[(size_t)(b0 + row) * 192 + c8 * 8];
    }
    __syncthreads();

    f32x4 accA[2][4] = {};
    f32x4 accB[2][4] = {};
    const _Float16* W2a = W2;
    const _Float16* W2b = W2 + 2048 * 192;

    #pragma unroll
    for (int ks = 0; ks < 6; ++ks) {
        int kk0 = ks * 32;
        half8 aA = *(const half8*)&TaSh[w * 16 + l15][kk0 + quad * 8];
        half8 aB = *(const half8*)&TbSh[w * 16 + l15][kk0 + quad * 8];
        #pragma unroll
        for (int g01 = 0; g01 < 2; ++g01) {
            #pragma unroll
            for (int nt = 0; nt < 4; ++nt) {
                int v = g01 * 1024 + kr + nt * 16 + l15;
                half8 bA = *(const half8*)&W2a[(size_t)v * 192 + kk0 + quad * 8];
                accA[g01][nt] = __builtin_amdgcn_mfma_f32_16x16x32_f16(aA, bA, accA[g01][nt], 0, 0, 0);
                half8 bB = *(const half8*)&W2b[(size_t)v * 192 + kk0 + quad * 8];
                accB[g01][nt] = __builtin_amdgcn_mfma_f32_16x16x32_f16(aB, bB, accB[g01][nt], 0, 0, 0);
            }
        }
    }

    // epilogue: acc element (nt, r): k = kr + 16*nt + l15, row = b0 + 16w + 4*quad + r
    #pragma unroll
    for (int nt = 0; nt < 4; ++nt) {
        int k = kr + nt * 16 + l15;
        float cxi = cx[k],        cxf = cx[1024 + k], cxo = cx[2048 + k], cxn = cx[3072 + k];
        float chi = ch[k],        chf = ch[1024 + k], cho = ch[2048 + k], chn = ch[3072 + k];
        float bbi = bb[k],        bbf = bb[1024 + k], bbo = bb[2048 + k], bbn = bb[3072 + k];
        #pragma unroll
        for (int r = 0; r < 4; ++r) {
            int row = b0 + w * 16 + quad * 4 + r;
            float xv = x[(size_t)row * 1024 + k];
            float hv = h[(size_t)row * 1024 + k];
            float cv = c[(size_t)row * 1024 + k];
            float pi = accA[0][nt][r] + xv * cxi + hv * chi + bbi;
            float pf = accA[1][nt][r] + xv * cxf + hv * chf + bbf;
            float po = accB[0][nt][r] + xv * cxo + hv * cho + bbo;
            float pn = accB[1][nt][r] + xv * cxn + hv * chn + bbn;
            float ig = 1.f / (1.f + __expf(-pi));
            float fg = 1.f / (1.f + __expf(-pf));
            float og = 1.f / (1.f + __expf(-po));
            float ng = tanhf(pn);
            float cn = fg * cv + ig * ng;
            float hn = og * tanhf(cn);
            out[(size_t)row * 1024 + k] = hn;
            out[(size_t)8388608 + (size_t)row * 1024 + k] = cn;
        }
    }
}

// ---------------------------------------------------------------------------
extern "C" void kernel_launch(void* const* d_in, const int* in_sizes, int n_in,
                              void* d_out, int out_size, void* d_ws, size_t ws_size,
                              hipStream_t stream)
{
    const float* x      = (const float*)d_in[0];
    const float* h      = (const float*)d_in[1];
    const float* c      = (const float*)d_in[2];
    const float* dia_x  = (const float*)d_in[3];
    const float* dia_h  = (const float*)d_in[4];
    const float* Ux     = (const float*)d_in[5];
    const float* Vx     = (const float*)d_in[6];
    const float* Uh0    = (const float*)d_in[7];
    const float* Vh0    = (const float*)d_in[8];
    const float* Uh1    = (const float*)d_in[9];
    const float* Vh1    = (const float*)d_in[10];
    const float* bias_x = (const float*)d_in[11];
    const float* bias_h = (const float*)d_in[12];
    float* out = (float*)d_out;

    char* ws = (char*)d_ws;
    _Float16* TaW = (_Float16*)(ws + WS_TA);
    _Float16* TbW = (_Float16*)(ws + WS_TB);
    _Float16* Uxt = (_Float16*)(ws + WS_UXT);
    _Float16* Uht = (_Float16*)(ws + WS_UHT);
    _Float16* W2  = (_Float16*)(ws + WS_W2);
    float* cx = (float*)(ws + WS_CX);
    float* ch = (float*)(ws + WS_CH);
    float* bb = (float*)(ws + WS_BB);

    prep_kernel<<<3856, 256, 0, stream>>>(Ux, Vx, Uh0, Vh0, Uh1, Vh1,
                                          dia_x, dia_h, bias_x, bias_h,
                                          Uxt, Uht, W2, cx, ch, bb);
    s1_kernel<<<dim3(128, 3), 256, 0, stream>>>(x, h, Uxt, Uht, TaW, TbW);
    s2_kernel<<<dim3(128, 16), 256, 0, stream>>>(TaW, TbW, W2, cx, ch, bb,
                                                 x, h, c, out);
}

// Round 3
// 352.314 us; speedup vs baseline: 1.0161x; 1.0161x over previous
//
#include <hip/hip_runtime.h>

// ---------------------------------------------------------------------------
// VM-LSTM cell, B=8192, D=H=1024, G=2, WR=64, URANKS=[64,64]
//
//   prep : fp16 stage-1 weights (Uxt, Uht[4]); stage-2 weight W2f in
//          MFMA-fragment-major layout [sg][ct][ks][lane][8] (fp16);
//          per-gate correction vectors cx/ch/bb (4x1024 fp32).
//   s1   : Ta[b,0:192] = [x@Ux | h0@Uh0g0 | h1@Uh1g0]
//          Tb[b,0:192] = [x@Ux | h1@Uh0g1 | h0@Uh1g1]   (fp16, MFMA)
//   s2   : 16-row blocks, all 1024 cols; A-frags in registers, B-frags as
//          coalesced dwordx4 loads from W2f (L2-resident); fused LSTM
//          elementwise epilogue.
// Gates: sg=0 i, 1 f (use Ta); 2 o, 3 n (use Tb). jx(q)=q, jh(q)=q^1.
// ---------------------------------------------------------------------------

typedef _Float16 half8 __attribute__((ext_vector_type(8)));
typedef _Float16 half4v __attribute__((ext_vector_type(4)));
typedef float f32x4 __attribute__((ext_vector_type(4)));

#define NB 8192
#define NH 1024

// workspace offsets (bytes)
#define WS_TA   0                      // 8192*192 fp16 = 3145728
#define WS_TB   3145728
#define WS_UXT  6291456                // 64*1024 fp16 = 131072
#define WS_UHT  6422528                // 4*64*512 fp16 = 262144
#define WS_W2   6684672                // 2*2048*192 fp16 = 1572864 (frag-major)
#define WS_CX   8257536                // 4096 fp32
#define WS_CH   8273920
#define WS_BB   8290304

// ---------------------------------------------------------------------------
__global__ __launch_bounds__(256) void prep_kernel(
    const float* __restrict__ Ux, const float* __restrict__ Vx,
    const float* __restrict__ Uh0, const float* __restrict__ Vh0,
    const float* __restrict__ Uh1, const float* __restrict__ Vh1,
    const float* __restrict__ dia_x, const float* __restrict__ dia_h,
    const float* __restrict__ bias_x, const float* __restrict__ bias_h,
    _Float16* __restrict__ Uxt, _Float16* __restrict__ Uht,
    _Float16* __restrict__ W2f, float* __restrict__ cx,
    float* __restrict__ ch, float* __restrict__ bb)
{
    int e = blockIdx.x * 256 + threadIdx.x;
    if (e < 65536) {
        // Uxt[r][d] = Ux[d][r], stride 1024
        int r = e >> 10, d = e & 1023;
        Uxt[e] = (_Float16)Ux[d * 64 + r];
    } else if (e < 196608) {
        // Uht[j][r][n], j: 0=Uh0g0, 1=Uh1g0, 2=Uh0g1, 3=Uh1g1, stride 512
        int t = e - 65536;
        int j = t >> 15; int rem = t & 32767; int r = rem >> 9; int n = rem & 511;
        const float* src = (j == 0 || j == 2) ? Uh0 : Uh1;
        int g = (j >= 2) ? 1 : 0;
        Uht[t] = (_Float16)src[(g * 512 + n) * 64 + r];
    } else if (e < 294912) {
        // W2f fragment-major: t = (((s*2+g01)*64 + ct)*6 + ks)*64 + lane,
        // each thread writes 8 contiguous halves (one lane's B-fragment slice).
        int t = e - 196608;                // 0..98303
        int lane = t & 63;
        int ksq  = (t >> 6) % 6;
        int ct   = (t / 384) & 63;
        int g01  = (t / 24576) & 1;
        int s    = t / 49152;
        int l15 = lane & 15, quad = lane >> 4;
        int k = ct * 16 + l15;             // 0..1023 (output column)
        int jx = s * 2 + g01;              // gx gate block
        int m = (g01 == 0) ? (1024 + k) : k;
        half8 v8;
        #pragma unroll
        for (int jj = 0; jj < 8; ++jj) {
            int kk = ksq * 32 + quad * 8 + jj;   // K index 0..191
            int r = kk & 63, sect = kk >> 6;
            float val;
            if (sect == 0)      val = Vx[(jx * 1024 + k) * 64 + r];
            else if (sect == 1) val = Vh0[(s * 64 + r) * 2048 + m];
            else                val = Vh1[(s * 64 + r) * 2048 + m];
            v8[jj] = (_Float16)val;
        }
        *(half8*)&W2f[(size_t)t * 8] = v8;
    } else if (e < 299008) {
        // correction vectors, q in {0:i,1:f,2:o,3:n}
        int t = e - 294912; int q = t >> 10; int k = t & 1023;
        int jh = q ^ 1;
        int fh = jh * 1024 + k; int g = fh >> 11; int m = fh & 2047;
        float sx = 0.f, sh = 0.f;
        for (int r = 0; r < 64; ++r) {
            sx += Ux[k * 64 + r] * Vx[(q * 1024 + k) * 64 + r];
            sh += Uh0[k * 64 + r] * Vh0[(g * 64 + r) * 2048 + m];
        }
        cx[t] = dia_x[k] - sx;
        ch[t] = dia_h[k] - sh;
        bb[t] = bias_x[q * 1024 + k] + bias_h[jh * 1024 + k];
    }
}

// ---------------------------------------------------------------------------
// Stage 1 (unchanged): 64-row x 128-col tiles, MFMA 16x16x32 f16.
__global__ __launch_bounds__(256) void s1_kernel(
    const float* __restrict__ x, const float* __restrict__ h,
    const _Float16* __restrict__ Uxt, const _Float16* __restrict__ Uht,
    _Float16* __restrict__ Ta, _Float16* __restrict__ Tb)
{
    __shared__ __align__(16) _Float16 Ash[64][72];
    __shared__ __align__(16) _Float16 Bsh[128][72];

    const int job = blockIdx.y;
    const int b0 = blockIdx.x * 64;
    const int tid = threadIdx.x;
    const int w = tid >> 6, l = tid & 63, l15 = l & 15, quad = l >> 4;

    const float* src; int koff, K;
    const _Float16 *Wa, *Wb; int colA, colB;
    if (job == 0)      { src = x; koff = 0;   K = 1024; Wa = Uxt;             Wb = Uxt;             colA = 0;   colB = 0;  }
    else if (job == 1) { src = h; koff = 0;   K = 512;  Wa = Uht;             Wb = Uht + 3 * 32768; colA = 64;  colB = 128; }
    else               { src = h; koff = 512; K = 512;  Wa = Uht + 32768;     Wb = Uht + 2 * 32768; colA = 128; colB = 64; }

    f32x4 acc[8] = {};
    const int nkb = K >> 6;
    for (int kb = 0; kb < nkb; ++kb) {
        #pragma unroll
        for (int ii = 0; ii < 4; ++ii) {
            int idx = tid + ii * 256;
            int row = idx >> 4, c4 = idx & 15;
            float4 f = *(const float4*)&src[(size_t)(b0 + row) * 1024 + koff + kb * 64 + c4 * 4];
            half4v p;
            p[0] = (_Float16)f.x; p[1] = (_Float16)f.y;
            p[2] = (_Float16)f.z; p[3] = (_Float16)f.w;
            *(half4v*)&Ash[row][c4 * 4] = p;
        }
        #pragma unroll
        for (int ii = 0; ii < 4; ++ii) {
            int idx = tid + ii * 256;
            int n = idx >> 3, c8 = idx & 7;
            const _Float16* Wp = (n < 64) ? (Wa + (size_t)n * K) : (Wb + (size_t)(n - 64) * K);
            *(half8*)&Bsh[n][c8 * 8] = *(const half8*)&Wp[kb * 64 + c8 * 8];
        }
        __syncthreads();
        #pragma unroll
        for (int kk0 = 0; kk0 < 64; kk0 += 32) {
            half8 a = *(const half8*)&Ash[w * 16 + l15][kk0 + quad * 8];
            #pragma unroll
            for (int nt = 0; nt < 8; ++nt) {
                half8 b = *(const half8*)&Bsh[nt * 16 + l15][kk0 + quad * 8];
                acc[nt] = __builtin_amdgcn_mfma_f32_16x16x32_f16(a, b, acc[nt], 0, 0, 0);
            }
        }
        __syncthreads();
    }
    #pragma unroll
    for (int nt = 0; nt < 8; ++nt) {
        _Float16* dst = (nt < 4) ? Ta : Tb;
        int col = ((nt < 4) ? colA : colB) + (nt & 3) * 16 + l15;
        #pragma unroll
        for (int r = 0; r < 4; ++r) {
            int row = b0 + w * 16 + quad * 4 + r;
            dst[(size_t)row * 192 + col] = (_Float16)acc[nt][r];
        }
    }
}

// ---------------------------------------------------------------------------
// Stage 2 v2: 16-row blocks (grid 512), each covers ALL 1024 k-cols.
//  - Ta/Tb rows staged to LDS once; A-fragments preloaded to registers.
//  - B-fragments: coalesced dwordx4 loads from frag-major W2f (L2-resident).
//  - kr loop: 24 B-loads + 24 MFMA + fused LSTM elementwise per wave.
__global__ __launch_bounds__(256, 2) void s2_kernel(
    const _Float16* __restrict__ Ta, const _Float16* __restrict__ Tb,
    const _Float16* __restrict__ W2f,
    const float* __restrict__ cx, const float* __restrict__ ch,
    const float* __restrict__ bb,
    const float* __restrict__ x, const float* __restrict__ h,
    const float* __restrict__ c, float* __restrict__ out)
{
    __shared__ __align__(16) _Float16 TaSh[16][200];
    __shared__ __align__(16) _Float16 TbSh[16][200];

    const int b0 = blockIdx.x * 16;
    const int tid = threadIdx.x;
    const int w = tid >> 6, l = tid & 63, l15 = l & 15, quad = l >> 4;

    // stage Ta/Tb tiles (16 rows x 192) -- coalesced half8 loads.
    // NOTE: 384 is NOT a pow2 -- must use subtraction, not `& 383`
    // (R2 bug: `idx & 383` left TbSh chunks 128..255 uninitialized -> NaN).
    #pragma unroll
    for (int ii = 0; ii < 3; ++ii) {
        int idx = tid + ii * 256;          // 0..767
        int arr = idx >= 384;
        int i2 = idx - (arr ? 384 : 0);    // 0..383 within each array
        int row = i2 / 24, c8 = i2 % 24;
        const _Float16* src = arr ? Tb : Ta;
        _Float16* dst = arr ? &TbSh[row][c8 * 8] : &TaSh[row][c8 * 8];
        *(half8*)dst = *(const half8*)&src[(size_t)(b0 + row) * 192 + c8 * 8];
    }
    __syncthreads();

    // A-fragments for all 6 k-steps (m = l15, k = ks*32 + quad*8 + j)
    half8 aA[6], aB[6];
    #pragma unroll
    for (int ks = 0; ks < 6; ++ks) {
        aA[ks] = *(const half8*)&TaSh[l15][ks * 32 + quad * 8];
        aB[ks] = *(const half8*)&TbSh[l15][ks * 32 + quad * 8];
    }

    const size_t laneoff = (size_t)l * 8;

    #pragma unroll 1
    for (int kr = 0; kr < 16; ++kr) {
        const int ctg = kr * 4 + w;        // global col-tile 0..63
        const int k = ctg * 16 + l15;      // this lane's output column
        f32x4 acc[4] = {};                 // sg: 0=i,1=f,2=o,3=n
        #pragma unroll
        for (int sg = 0; sg < 4; ++sg) {
            const _Float16* bp = W2f + (size_t)((sg * 64 + ctg) * 6) * 512 + laneoff;
            #pragma unroll
            for (int ks = 0; ks < 6; ++ks) {
                half8 b = *(const half8*)(bp + (size_t)ks * 512);
                acc[sg] = __builtin_amdgcn_mfma_f32_16x16x32_f16(
                    (sg < 2) ? aA[ks] : aB[ks], b, acc[sg], 0, 0, 0);
            }
        }
        // fused elementwise epilogue (D: col=l15 -> k, row=quad*4+r -> batch)
        float cxi = cx[k], cxf = cx[1024 + k], cxo = cx[2048 + k], cxn = cx[3072 + k];
        float chi = ch[k], chf = ch[1024 + k], cho = ch[2048 + k], chn = ch[3072 + k];
        float bbi = bb[k], bbf = bb[1024 + k], bbo = bb[2048 + k], bbn = bb[3072 + k];
        #pragma unroll
        for (int r = 0; r < 4; ++r) {
            int row = b0 + quad * 4 + r;
            size_t off = (size_t)row * 1024 + k;
            float xv = x[off], hv = h[off], cv = c[off];
            float pi = acc[0][r] + xv * cxi + hv * chi + bbi;
            float pf = acc[1][r] + xv * cxf + hv * chf + bbf;
            float po = acc[2][r] + xv * cxo + hv * cho + bbo;
            float pn = acc[3][r] + xv * cxn + hv * chn + bbn;
            float ig = 1.f / (1.f + __expf(-pi));
            float fg = 1.f / (1.f + __expf(-pf));
            float og = 1.f / (1.f + __expf(-po));
            float e2n = __expf(2.f * pn);
            float ng = 1.f - 2.f / (e2n + 1.f);
            float cn = fg * cv + ig * ng;
            float e2c = __expf(2.f * cn);
            float tc = 1.f - 2.f / (e2c + 1.f);
            out[off] = og * tc;
            out[(size_t)8388608 + off] = cn;
        }
    }
}

// ---------------------------------------------------------------------------
extern "C" void kernel_launch(void* const* d_in, const int* in_sizes, int n_in,
                              void* d_out, int out_size, void* d_ws, size_t ws_size,
                              hipStream_t stream)
{
    const float* x      = (const float*)d_in[0];
    const float* h      = (const float*)d_in[1];
    const float* c      = (const float*)d_in[2];
    const float* dia_x  = (const float*)d_in[3];
    const float* dia_h  = (const float*)d_in[4];
    const float* Ux     = (const float*)d_in[5];
    const float* Vx     = (const float*)d_in[6];
    const float* Uh0    = (const float*)d_in[7];
    const float* Vh0    = (const float*)d_in[8];
    const float* Uh1    = (const float*)d_in[9];
    const float* Vh1    = (const float*)d_in[10];
    const float* bias_x = (const float*)d_in[11];
    const float* bias_h = (const float*)d_in[12];
    float* out = (float*)d_out;

    char* ws = (char*)d_ws;
    _Float16* TaW = (_Float16*)(ws + WS_TA);
    _Float16* TbW = (_Float16*)(ws + WS_TB);
    _Float16* Uxt = (_Float16*)(ws + WS_UXT);
    _Float16* Uht = (_Float16*)(ws + WS_UHT);
    _Float16* W2f = (_Float16*)(ws + WS_W2);
    float* cx = (float*)(ws + WS_CX);
    float* ch = (float*)(ws + WS_CH);
    float* bb = (float*)(ws + WS_BB);

    prep_kernel<<<1168, 256, 0, stream>>>(Ux, Vx, Uh0, Vh0, Uh1, Vh1,
                                          dia_x, dia_h, bias_x, bias_h,
                                          Uxt, Uht, W2f, cx, ch, bb);
    s1_kernel<<<dim3(128, 3), 256, 0, stream>>>(x, h, Uxt, Uht, TaW, TbW);
    s2_kernel<<<512, 256, 0, stream>>>(TaW, TbW, W2f, cx, ch, bb,
                                       x, h, c, out);
}

// Round 4
// 250.977 us; speedup vs baseline: 1.4264x; 1.4038x over previous
//
#include <hip/hip_runtime.h>

// ---------------------------------------------------------------------------
// VM-LSTM cell, B=8192, D=H=1024, G=2, WR=64, URANKS=[64,64]
//
//   prep : stage-1 weights in MFMA-frag-major fp16 (U1f: x@Ux, Uh1f: 4 h-mats);
//          stage-2 weight W2f frag-major fp16; correction vectors cx/ch/bb.
//   s1   : 16-row blocks, grid (512,3). A-tile (x or h chunk) in LDS,
//          B-frags straight from global (L2-hot, coalesced 1KB/load).
//          Ta[b,0:192] = [x@Ux | h0@Uh0g0 | h1@Uh1g0]
//          Tb[b,0:192] = [x@Ux | h1@Uh0g1 | h0@Uh1g1]
//   s2   : grid (512 rows x 4 col-quarters) = 2048 blocks for occupancy;
//          A-frags in regs, B-frags coalesced from W2f; fused LSTM epilogue.
// Gates: sg=0 i, 1 f (use Ta); 2 o, 3 n (use Tb). jx(q)=q, jh(q)=q^1.
// ---------------------------------------------------------------------------

typedef _Float16 half8 __attribute__((ext_vector_type(8)));
typedef _Float16 half4v __attribute__((ext_vector_type(4)));
typedef float f32x4 __attribute__((ext_vector_type(4)));

// workspace offsets (bytes)
#define WS_TA    0                     // 8192*192 fp16 = 3145728
#define WS_TB    3145728
#define WS_U1F   6291456               // 4*32*64*8 fp16 = 131072 B
#define WS_UH1F  6422528               // 4*4*16*64*8 fp16 = 262144 B
#define WS_W2    6684672               // 2*2048*192 fp16 = 1572864 (frag-major)
#define WS_CX    8257536               // 4096 fp32
#define WS_CH    8273920
#define WS_BB    8290304

// ---------------------------------------------------------------------------
__global__ __launch_bounds__(256) void prep_kernel(
    const float* __restrict__ Ux, const float* __restrict__ Vx,
    const float* __restrict__ Uh0, const float* __restrict__ Vh0,
    const float* __restrict__ Uh1, const float* __restrict__ Vh1,
    const float* __restrict__ dia_x, const float* __restrict__ dia_h,
    const float* __restrict__ bias_x, const float* __restrict__ bias_h,
    _Float16* __restrict__ U1f, _Float16* __restrict__ Uh1f,
    _Float16* __restrict__ W2f, float* __restrict__ cx,
    float* __restrict__ ch, float* __restrict__ bb)
{
    int e = blockIdx.x * 256 + threadIdx.x;
    if (e < 8192) {
        // U1f[ct(4)][ks(32)][lane][8]: B-frag for x@Ux.
        // value = Ux[k][n], n = ct*16+l15, k = ks*32+quad*8+jj
        int lane = e & 63, ks = (e >> 6) & 31, ct = e >> 11;
        int l15 = lane & 15, quad = lane >> 4;
        half8 v8;
        #pragma unroll
        for (int jj = 0; jj < 8; ++jj) {
            int k = ks * 32 + quad * 8 + jj;
            v8[jj] = (_Float16)Ux[k * 64 + ct * 16 + l15];
        }
        *(half8*)&U1f[(size_t)e * 8] = v8;
    } else if (e < 24576) {
        // Uh1f[j(4)][ct(4)][ks(16)][lane][8]; j: 0=Uh0g0,1=Uh1g0,2=Uh0g1,3=Uh1g1
        // value = src[(g*512 + k)*64 + n], n = ct*16+l15 (rank), k = h-feature
        int t = e - 8192;
        int lane = t & 63, ks = (t >> 6) & 15, ct = (t >> 10) & 3, j = t >> 12;
        int l15 = lane & 15, quad = lane >> 4;
        const float* src = (j & 1) ? Uh1 : Uh0;
        int g = j >> 1;
        half8 v8;
        #pragma unroll
        for (int jj = 0; jj < 8; ++jj) {
            int k = ks * 32 + quad * 8 + jj;
            v8[jj] = (_Float16)src[(g * 512 + k) * 64 + ct * 16 + l15];
        }
        *(half8*)&Uh1f[(size_t)t * 8] = v8;
    } else if (e < 122880) {
        // W2f fragment-major: t = (((s*2+g01)*64 + ct)*6 + ks)*64 + lane
        int t = e - 24576;                 // 0..98303
        int lane = t & 63;
        int ksq  = (t >> 6) % 6;
        int ct   = (t / 384) & 63;
        int g01  = (t / 24576) & 1;
        int s    = t / 49152;
        int l15 = lane & 15, quad = lane >> 4;
        int k = ct * 16 + l15;             // output column
        int jx = s * 2 + g01;
        int m = (g01 == 0) ? (1024 + k) : k;
        half8 v8;
        #pragma unroll
        for (int jj = 0; jj < 8; ++jj) {
            int kk = ksq * 32 + quad * 8 + jj;   // K index 0..191
            int r = kk & 63, sect = kk >> 6;
            float val;
            if (sect == 0)      val = Vx[(jx * 1024 + k) * 64 + r];
            else if (sect == 1) val = Vh0[(s * 64 + r) * 2048 + m];
            else                val = Vh1[(s * 64 + r) * 2048 + m];
            v8[jj] = (_Float16)val;
        }
        *(half8*)&W2f[(size_t)t * 8] = v8;
    } else if (e < 126976) {
        // correction vectors, q in {0:i,1:f,2:o,3:n}
        int t = e - 122880; int q = t >> 10; int k = t & 1023;
        int jh = q ^ 1;
        int fh = jh * 1024 + k; int g = fh >> 11; int m = fh & 2047;
        float sx = 0.f, sh = 0.f;
        for (int r = 0; r < 64; ++r) {
            sx += Ux[k * 64 + r] * Vx[(q * 1024 + k) * 64 + r];
            sh += Uh0[k * 64 + r] * Vh0[(g * 64 + r) * 2048 + m];
        }
        cx[t] = dia_x[k] - sx;
        ch[t] = dia_h[k] - sh;
        bb[t] = bias_x[q * 1024 + k] + bias_h[jh * 1024 + k];
    }
}

// ---------------------------------------------------------------------------
// Stage 1 v2: 16-row blocks, grid (512,3). B-frags from global (frag-major),
// no B LDS staging, job0 writes x@Ux to BOTH Ta[0:64] and Tb[0:64].
__global__ __launch_bounds__(256) void s1_kernel(
    const float* __restrict__ x, const float* __restrict__ h,
    const _Float16* __restrict__ U1f, const _Float16* __restrict__ Uh1f,
    _Float16* __restrict__ Ta, _Float16* __restrict__ Tb)
{
    __shared__ __align__(16) _Float16 Ash[16][520];

    const int job = blockIdx.y;
    const int b0 = blockIdx.x * 16;
    const int tid = threadIdx.x;
    const int w = tid >> 6, l = tid & 63, l15 = l & 15, quad = l >> 4;

    f32x4 acc0 = {}, acc1 = {};
    const int nkc = (job == 0) ? 2 : 1;
    const float* src = (job == 0) ? x : h;

    for (int kc = 0; kc < nkc; ++kc) {
        const int koff = (job == 2) ? 512 : kc * 512;
        // stage 16 rows x 512 k, fp32 -> fp16, coalesced float4
        #pragma unroll
        for (int ii = 0; ii < 8; ++ii) {
            int idx = tid + ii * 256;      // 0..2047
            int row = idx >> 7, c4 = idx & 127;
            float4 f = *(const float4*)&src[(size_t)(b0 + row) * 1024 + koff + c4 * 4];
            half4v p;
            p[0] = (_Float16)f.x; p[1] = (_Float16)f.y;
            p[2] = (_Float16)f.z; p[3] = (_Float16)f.w;
            *(half4v*)&Ash[row][c4 * 4] = p;
        }
        __syncthreads();
        if (job == 0) {
            const _Float16* bp = U1f + ((size_t)(w * 32 + kc * 16) * 64 + l) * 8;
            #pragma unroll
            for (int ks = 0; ks < 16; ++ks) {
                half8 a = *(const half8*)&Ash[l15][ks * 32 + quad * 8];
                half8 b = *(const half8*)(bp + (size_t)ks * 512);
                acc0 = __builtin_amdgcn_mfma_f32_16x16x32_f16(a, b, acc0, 0, 0, 0);
            }
        } else {
            const int j0 = (job == 1) ? 0 : 1;   // -> Ta
            const int j1 = (job == 1) ? 3 : 2;   // -> Tb
            const _Float16* bp0 = Uh1f + ((size_t)((j0 * 4 + w) * 16) * 64 + l) * 8;
            const _Float16* bp1 = Uh1f + ((size_t)((j1 * 4 + w) * 16) * 64 + l) * 8;
            #pragma unroll
            for (int ks = 0; ks < 16; ++ks) {
                half8 a = *(const half8*)&Ash[l15][ks * 32 + quad * 8];
                half8 b0 = *(const half8*)(bp0 + (size_t)ks * 512);
                acc0 = __builtin_amdgcn_mfma_f32_16x16x32_f16(a, b0, acc0, 0, 0, 0);
                half8 b1 = *(const half8*)(bp1 + (size_t)ks * 512);
                acc1 = __builtin_amdgcn_mfma_f32_16x16x32_f16(a, b1, acc1, 0, 0, 0);
            }
        }
        __syncthreads();
    }
    // D layout: col = l15 (+ct*16), row = quad*4 + r
    if (job == 0) {
        int col = w * 16 + l15;
        #pragma unroll
        for (int r = 0; r < 4; ++r) {
            int row = b0 + quad * 4 + r;
            _Float16 v = (_Float16)acc0[r];
            Ta[(size_t)row * 192 + col] = v;
            Tb[(size_t)row * 192 + col] = v;
        }
    } else {
        int colA = ((job == 1) ? 64 : 128) + w * 16 + l15;
        int colB = ((job == 1) ? 128 : 64) + w * 16 + l15;
        #pragma unroll
        for (int r = 0; r < 4; ++r) {
            int row = b0 + quad * 4 + r;
            Ta[(size_t)row * 192 + colA] = (_Float16)acc0[r];
            Tb[(size_t)row * 192 + colB] = (_Float16)acc1[r];
        }
    }
}

// ---------------------------------------------------------------------------
// Stage 2 v3: grid (512 row-blocks x 4 col-quarters) = 2048 blocks -> 8/CU.
// Each block: 16 rows x 256 cols (4 kr iterations).
__global__ __launch_bounds__(256, 2) void s2_kernel(
    const _Float16* __restrict__ Ta, const _Float16* __restrict__ Tb,
    const _Float16* __restrict__ W2f,
    const float* __restrict__ cx, const float* __restrict__ ch,
    const float* __restrict__ bb,
    const float* __restrict__ x, const float* __restrict__ h,
    const float* __restrict__ c, float* __restrict__ out)
{
    __shared__ __align__(16) _Float16 TaSh[16][200];
    __shared__ __align__(16) _Float16 TbSh[16][200];

    const int b0 = blockIdx.x * 16;
    const int kr0 = blockIdx.y * 4;
    const int tid = threadIdx.x;
    const int w = tid >> 6, l = tid & 63, l15 = l & 15, quad = l >> 4;

    // stage Ta/Tb tiles (16 rows x 192). 384 is NOT pow2: subtract, don't mask.
    #pragma unroll
    for (int ii = 0; ii < 3; ++ii) {
        int idx = tid + ii * 256;          // 0..767
        int arr = idx >= 384;
        int i2 = idx - (arr ? 384 : 0);    // 0..383
        int row = i2 / 24, c8 = i2 % 24;
        const _Float16* src = arr ? Tb : Ta;
        _Float16* dst = arr ? &TbSh[row][c8 * 8] : &TaSh[row][c8 * 8];
        *(half8*)dst = *(const half8*)&src[(size_t)(b0 + row) * 192 + c8 * 8];
    }
    __syncthreads();

    // A-fragments for all 6 k-steps (m = l15, k = ks*32 + quad*8 + j)
    half8 aA[6], aB[6];
    #pragma unroll
    for (int ks = 0; ks < 6; ++ks) {
        aA[ks] = *(const half8*)&TaSh[l15][ks * 32 + quad * 8];
        aB[ks] = *(const half8*)&TbSh[l15][ks * 32 + quad * 8];
    }

    const size_t laneoff = (size_t)l * 8;

    #pragma unroll 1
    for (int kr = kr0; kr < kr0 + 4; ++kr) {
        const int ctg = kr * 4 + w;        // global col-tile 0..63
        const int k = ctg * 16 + l15;      // this lane's output column
        f32x4 acc[4] = {};                 // sg: 0=i,1=f,2=o,3=n
        #pragma unroll
        for (int sg = 0; sg < 4; ++sg) {
            const _Float16* bp = W2f + (size_t)((sg * 64 + ctg) * 6) * 512 + laneoff;
            #pragma unroll
            for (int ks = 0; ks < 6; ++ks) {
                half8 b = *(const half8*)(bp + (size_t)ks * 512);
                acc[sg] = __builtin_amdgcn_mfma_f32_16x16x32_f16(
                    (sg < 2) ? aA[ks] : aB[ks], b, acc[sg], 0, 0, 0);
            }
        }
        // fused elementwise epilogue (D: col=l15 -> k, row=quad*4+r -> batch)
        float cxi = cx[k], cxf = cx[1024 + k], cxo = cx[2048 + k], cxn = cx[3072 + k];
        float chi = ch[k], chf = ch[1024 + k], cho = ch[2048 + k], chn = ch[3072 + k];
        float bbi = bb[k], bbf = bb[1024 + k], bbo = bb[2048 + k], bbn = bb[3072 + k];
        #pragma unroll
        for (int r = 0; r < 4; ++r) {
            int row = b0 + quad * 4 + r;
            size_t off = (size_t)row * 1024 + k;
            float xv = x[off], hv = h[off], cv = c[off];
            float pi = acc[0][r] + xv * cxi + hv * chi + bbi;
            float pf = acc[1][r] + xv * cxf + hv * chf + bbf;
            float po = acc[2][r] + xv * cxo + hv * cho + bbo;
            float pn = acc[3][r] + xv * cxn + hv * chn + bbn;
            float ig = 1.f / (1.f + __expf(-pi));
            float fg = 1.f / (1.f + __expf(-pf));
            float og = 1.f / (1.f + __expf(-po));
            float e2n = __expf(2.f * pn);
            float ng = 1.f - 2.f / (e2n + 1.f);
            float cn = fg * cv + ig * ng;
            float e2c = __expf(2.f * cn);
            float tc = 1.f - 2.f / (e2c + 1.f);
            out[off] = og * tc;
            out[(size_t)8388608 + off] = cn;
        }
    }
}

// ---------------------------------------------------------------------------
extern "C" void kernel_launch(void* const* d_in, const int* in_sizes, int n_in,
                              void* d_out, int out_size, void* d_ws, size_t ws_size,
                              hipStream_t stream)
{
    const float* x      = (const float*)d_in[0];
    const float* h      = (const float*)d_in[1];
    const float* c      = (const float*)d_in[2];
    const float* dia_x  = (const float*)d_in[3];
    const float* dia_h  = (const float*)d_in[4];
    const float* Ux     = (const float*)d_in[5];
    const float* Vx     = (const float*)d_in[6];
    const float* Uh0    = (const float*)d_in[7];
    const float* Vh0    = (const float*)d_in[8];
    const float* Uh1    = (const float*)d_in[9];
    const float* Vh1    = (const float*)d_in[10];
    const float* bias_x = (const float*)d_in[11];
    const float* bias_h = (const float*)d_in[12];
    float* out = (float*)d_out;

    char* ws = (char*)d_ws;
    _Float16* TaW  = (_Float16*)(ws + WS_TA);
    _Float16* TbW  = (_Float16*)(ws + WS_TB);
    _Float16* U1f  = (_Float16*)(ws + WS_U1F);
    _Float16* Uh1f = (_Float16*)(ws + WS_UH1F);
    _Float16* W2f  = (_Float16*)(ws + WS_W2);
    float* cx = (float*)(ws + WS_CX);
    float* ch = (float*)(ws + WS_CH);
    float* bb = (float*)(ws + WS_BB);

    prep_kernel<<<496, 256, 0, stream>>>(Ux, Vx, Uh0, Vh0, Uh1, Vh1,
                                         dia_x, dia_h, bias_x, bias_h,
                                         U1f, Uh1f, W2f, cx, ch, bb);
    s1_kernel<<<dim3(512, 3), 256, 0, stream>>>(x, h, U1f, Uh1f, TaW, TbW);
    s2_kernel<<<dim3(512, 4), 256, 0, stream>>>(TaW, TbW, W2f, cx, ch, bb,
                                                x, h, c, out);
}

// Round 5
// 244.557 us; speedup vs baseline: 1.4639x; 1.0263x over previous
//
#include <hip/hip_runtime.h>

// ---------------------------------------------------------------------------
// VM-LSTM cell, B=8192, D=H=1024, G=2, WR=64, URANKS=[64,64]
//
//   prep : stage-1 weights in MFMA-frag-major fp16 (U1f: x@Ux, Uh1f: 4 h-mats);
//          stage-2 weight W2f frag-major fp16; correction vectors cx/ch/bb.
//   s1   : 16-row blocks, grid (512,3). A-tile (x or h chunk) in LDS,
//          B-frags straight from global (L2-hot, coalesced 1KB/load).
//   s2 v4: 32-row x 128-col blocks, grid (256,8) = 2048. Each B-frag load
//          feeds 2 MFMAs (two 16-row tiles) -> W2f traffic halved; A-frags
//          via ds_read_b128 in-loop; rcp-based sigmoid/tanh epilogue.
// Gates: sg=0 i, 1 f (use Ta); 2 o, 3 n (use Tb). jx(q)=q, jh(q)=q^1.
// ---------------------------------------------------------------------------

typedef _Float16 half8 __attribute__((ext_vector_type(8)));
typedef _Float16 half4v __attribute__((ext_vector_type(4)));
typedef float f32x4 __attribute__((ext_vector_type(4)));

// workspace offsets (bytes)
#define WS_TA    0                     // 8192*192 fp16 = 3145728
#define WS_TB    3145728
#define WS_U1F   6291456               // 131072 B
#define WS_UH1F  6422528               // 262144 B
#define WS_W2    6684672               // 1572864 B (frag-major)
#define WS_CX    8257536               // 4096 fp32
#define WS_CH    8273920
#define WS_BB    8290304

// ---------------------------------------------------------------------------
__global__ __launch_bounds__(256) void prep_kernel(
    const float* __restrict__ Ux, const float* __restrict__ Vx,
    const float* __restrict__ Uh0, const float* __restrict__ Vh0,
    const float* __restrict__ Uh1, const float* __restrict__ Vh1,
    const float* __restrict__ dia_x, const float* __restrict__ dia_h,
    const float* __restrict__ bias_x, const float* __restrict__ bias_h,
    _Float16* __restrict__ U1f, _Float16* __restrict__ Uh1f,
    _Float16* __restrict__ W2f, float* __restrict__ cx,
    float* __restrict__ ch, float* __restrict__ bb)
{
    int e = blockIdx.x * 256 + threadIdx.x;
    if (e < 8192) {
        // U1f[ct(4)][ks(32)][lane][8]: B-frag for x@Ux.
        int lane = e & 63, ks = (e >> 6) & 31, ct = e >> 11;
        int l15 = lane & 15, quad = lane >> 4;
        half8 v8;
        #pragma unroll
        for (int jj = 0; jj < 8; ++jj) {
            int k = ks * 32 + quad * 8 + jj;
            v8[jj] = (_Float16)Ux[k * 64 + ct * 16 + l15];
        }
        *(half8*)&U1f[(size_t)e * 8] = v8;
    } else if (e < 24576) {
        // Uh1f[j(4)][ct(4)][ks(16)][lane][8]; j: 0=Uh0g0,1=Uh1g0,2=Uh0g1,3=Uh1g1
        int t = e - 8192;
        int lane = t & 63, ks = (t >> 6) & 15, ct = (t >> 10) & 3, j = t >> 12;
        int l15 = lane & 15, quad = lane >> 4;
        const float* src = (j & 1) ? Uh1 : Uh0;
        int g = j >> 1;
        half8 v8;
        #pragma unroll
        for (int jj = 0; jj < 8; ++jj) {
            int k = ks * 32 + quad * 8 + jj;
            v8[jj] = (_Float16)src[(g * 512 + k) * 64 + ct * 16 + l15];
        }
        *(half8*)&Uh1f[(size_t)t * 8] = v8;
    } else if (e < 122880) {
        // W2f fragment-major: t = (((s*2+g01)*64 + ct)*6 + ks)*64 + lane
        int t = e - 24576;                 // 0..98303
        int lane = t & 63;
        int ksq  = (t >> 6) % 6;
        int ct   = (t / 384) & 63;
        int g01  = (t / 24576) & 1;
        int s    = t / 49152;
        int l15 = lane & 15, quad = lane >> 4;
        int k = ct * 16 + l15;             // output column
        int jx = s * 2 + g01;
        int m = (g01 == 0) ? (1024 + k) : k;
        half8 v8;
        #pragma unroll
        for (int jj = 0; jj < 8; ++jj) {
            int kk = ksq * 32 + quad * 8 + jj;   // K index 0..191
            int r = kk & 63, sect = kk >> 6;
            float val;
            if (sect == 0)      val = Vx[(jx * 1024 + k) * 64 + r];
            else if (sect == 1) val = Vh0[(s * 64 + r) * 2048 + m];
            else                val = Vh1[(s * 64 + r) * 2048 + m];
            v8[jj] = (_Float16)val;
        }
        *(half8*)&W2f[(size_t)t * 8] = v8;
    } else if (e < 126976) {
        // correction vectors, q in {0:i,1:f,2:o,3:n}
        int t = e - 122880; int q = t >> 10; int k = t & 1023;
        int jh = q ^ 1;
        int fh = jh * 1024 + k; int g = fh >> 11; int m = fh & 2047;
        float sx = 0.f, sh = 0.f;
        for (int r = 0; r < 64; ++r) {
            sx += Ux[k * 64 + r] * Vx[(q * 1024 + k) * 64 + r];
            sh += Uh0[k * 64 + r] * Vh0[(g * 64 + r) * 2048 + m];
        }
        cx[t] = dia_x[k] - sx;
        ch[t] = dia_h[k] - sh;
        bb[t] = bias_x[q * 1024 + k] + bias_h[jh * 1024 + k];
    }
}

// ---------------------------------------------------------------------------
// Stage 1 (unchanged from R4): 16-row blocks, grid (512,3).
__global__ __launch_bounds__(256) void s1_kernel(
    const float* __restrict__ x, const float* __restrict__ h,
    const _Float16* __restrict__ U1f, const _Float16* __restrict__ Uh1f,
    _Float16* __restrict__ Ta, _Float16* __restrict__ Tb)
{
    __shared__ __align__(16) _Float16 Ash[16][520];

    const int job = blockIdx.y;
    const int b0 = blockIdx.x * 16;
    const int tid = threadIdx.x;
    const int w = tid >> 6, l = tid & 63, l15 = l & 15, quad = l >> 4;

    f32x4 acc0 = {}, acc1 = {};
    const int nkc = (job == 0) ? 2 : 1;
    const float* src = (job == 0) ? x : h;

    for (int kc = 0; kc < nkc; ++kc) {
        const int koff = (job == 2) ? 512 : kc * 512;
        #pragma unroll
        for (int ii = 0; ii < 8; ++ii) {
            int idx = tid + ii * 256;      // 0..2047
            int row = idx >> 7, c4 = idx & 127;
            float4 f = *(const float4*)&src[(size_t)(b0 + row) * 1024 + koff + c4 * 4];
            half4v p;
            p[0] = (_Float16)f.x; p[1] = (_Float16)f.y;
            p[2] = (_Float16)f.z; p[3] = (_Float16)f.w;
            *(half4v*)&Ash[row][c4 * 4] = p;
        }
        __syncthreads();
        if (job == 0) {
            const _Float16* bp = U1f + ((size_t)(w * 32 + kc * 16) * 64 + l) * 8;
            #pragma unroll
            for (int ks = 0; ks < 16; ++ks) {
                half8 a = *(const half8*)&Ash[l15][ks * 32 + quad * 8];
                half8 b = *(const half8*)(bp + (size_t)ks * 512);
                acc0 = __builtin_amdgcn_mfma_f32_16x16x32_f16(a, b, acc0, 0, 0, 0);
            }
        } else {
            const int j0 = (job == 1) ? 0 : 1;   // -> Ta
            const int j1 = (job == 1) ? 3 : 2;   // -> Tb
            const _Float16* bp0 = Uh1f + ((size_t)((j0 * 4 + w) * 16) * 64 + l) * 8;
            const _Float16* bp1 = Uh1f + ((size_t)((j1 * 4 + w) * 16) * 64 + l) * 8;
            #pragma unroll
            for (int ks = 0; ks < 16; ++ks) {
                half8 a = *(const half8*)&Ash[l15][ks * 32 + quad * 8];
                half8 b0 = *(const half8*)(bp0 + (size_t)ks * 512);
                acc0 = __builtin_amdgcn_mfma_f32_16x16x32_f16(a, b0, acc0, 0, 0, 0);
                half8 b1 = *(const half8*)(bp1 + (size_t)ks * 512);
                acc1 = __builtin_amdgcn_mfma_f32_16x16x32_f16(a, b1, acc1, 0, 0, 0);
            }
        }
        __syncthreads();
    }
    if (job == 0) {
        int col = w * 16 + l15;
        #pragma unroll
        for (int r = 0; r < 4; ++r) {
            int row = b0 + quad * 4 + r;
            _Float16 v = (_Float16)acc0[r];
            Ta[(size_t)row * 192 + col] = v;
            Tb[(size_t)row * 192 + col] = v;
        }
    } else {
        int colA = ((job == 1) ? 64 : 128) + w * 16 + l15;
        int colB = ((job == 1) ? 128 : 64) + w * 16 + l15;
        #pragma unroll
        for (int r = 0; r < 4; ++r) {
            int row = b0 + quad * 4 + r;
            Ta[(size_t)row * 192 + colA] = (_Float16)acc0[r];
            Tb[(size_t)row * 192 + colB] = (_Float16)acc1[r];
        }
    }
}

// ---------------------------------------------------------------------------
// Stage 2 v4: 32 rows x 128 cols per block, grid (256, 8) = 2048 blocks.
// Each B-frag load feeds 2 MFMAs (row-tiles rt=0,1): W2f traffic halved.
// A-frags via ds_read_b128 in-loop (shared across gate pair), acc in AGPRs.
__global__ __launch_bounds__(256, 4) void s2_kernel(
    const _Float16* __restrict__ Ta, const _Float16* __restrict__ Tb,
    const _Float16* __restrict__ W2f,
    const float* __restrict__ cx, const float* __restrict__ ch,
    const float* __restrict__ bb,
    const float* __restrict__ x, const float* __restrict__ h,
    const float* __restrict__ c, float* __restrict__ out)
{
    __shared__ __align__(16) _Float16 TaSh[32][200];
    __shared__ __align__(16) _Float16 TbSh[32][200];

    const int b0 = blockIdx.x * 32;
    const int by = blockIdx.y;             // 128-col slab: ctg = by*8+kr*4+w
    const int tid = threadIdx.x;
    const int w = tid >> 6, l = tid & 63, l15 = l & 15, quad = l >> 4;

    // stage Ta/Tb tiles (32 rows x 192). 768 is NOT pow2: subtract, don't mask.
    #pragma unroll
    for (int ii = 0; ii < 6; ++ii) {
        int idx = tid + ii * 256;          // 0..1535
        int arr = idx >= 768;
        int i2 = idx - (arr ? 768 : 0);    // 0..767
        int row = i2 / 24, c8 = i2 % 24;
        const _Float16* src = arr ? Tb : Ta;
        _Float16* dst = arr ? &TbSh[row][c8 * 8] : &TaSh[row][c8 * 8];
        *(half8*)dst = *(const half8*)&src[(size_t)(b0 + row) * 192 + c8 * 8];
    }
    __syncthreads();

    const size_t laneoff = (size_t)l * 8;

    #pragma unroll
    for (int kr = 0; kr < 2; ++kr) {
        const int ctg = by * 8 + kr * 4 + w;   // global col-tile 0..63
        const int k = ctg * 16 + l15;          // this lane's output column
        f32x4 acc[4][2] = {};                  // [sg][row-tile]
        const _Float16* bpi = W2f + (size_t)((0 * 64 + ctg) * 6) * 512 + laneoff;
        const _Float16* bpf = W2f + (size_t)((1 * 64 + ctg) * 6) * 512 + laneoff;
        const _Float16* bpo = W2f + (size_t)((2 * 64 + ctg) * 6) * 512 + laneoff;
        const _Float16* bpn = W2f + (size_t)((3 * 64 + ctg) * 6) * 512 + laneoff;
        #pragma unroll
        for (int ks = 0; ks < 6; ++ks) {
            half8 bi = *(const half8*)(bpi + (size_t)ks * 512);
            half8 bf = *(const half8*)(bpf + (size_t)ks * 512);
            half8 bo = *(const half8*)(bpo + (size_t)ks * 512);
            half8 bn = *(const half8*)(bpn + (size_t)ks * 512);
            #pragma unroll
            for (int rt = 0; rt < 2; ++rt) {
                half8 aA = *(const half8*)&TaSh[rt * 16 + l15][ks * 32 + quad * 8];
                half8 aB = *(const half8*)&TbSh[rt * 16 + l15][ks * 32 + quad * 8];
                acc[0][rt] = __builtin_amdgcn_mfma_f32_16x16x32_f16(aA, bi, acc[0][rt], 0, 0, 0);
                acc[1][rt] = __builtin_amdgcn_mfma_f32_16x16x32_f16(aA, bf, acc[1][rt], 0, 0, 0);
                acc[2][rt] = __builtin_amdgcn_mfma_f32_16x16x32_f16(aB, bo, acc[2][rt], 0, 0, 0);
                acc[3][rt] = __builtin_amdgcn_mfma_f32_16x16x32_f16(aB, bn, acc[3][rt], 0, 0, 0);
            }
        }
        // fused elementwise epilogue (D: col=l15 -> k, row=quad*4+r -> batch)
        float cxi = cx[k], cxf = cx[1024 + k], cxo = cx[2048 + k], cxn = cx[3072 + k];
        float chi = ch[k], chf = ch[1024 + k], cho = ch[2048 + k], chn = ch[3072 + k];
        float bbi = bb[k], bbf = bb[1024 + k], bbo = bb[2048 + k], bbn = bb[3072 + k];
        #pragma unroll
        for (int rt = 0; rt < 2; ++rt) {
            #pragma unroll
            for (int r = 0; r < 4; ++r) {
                int row = b0 + rt * 16 + quad * 4 + r;
                size_t off = (size_t)row * 1024 + k;
                float xv = x[off], hv = h[off], cv = c[off];
                float pi = acc[0][rt][r] + xv * cxi + hv * chi + bbi;
                float pf = acc[1][rt][r] + xv * cxf + hv * chf + bbf;
                float po = acc[2][rt][r] + xv * cxo + hv * cho + bbo;
                float pn = acc[3][rt][r] + xv * cxn + hv * chn + bbn;
                // sigmoid/tanh via fast rcp (tolerance 0.115 >> rcp error)
                float ig = __builtin_amdgcn_rcpf(1.f + __expf(-pi));
                float fg = __builtin_amdgcn_rcpf(1.f + __expf(-pf));
                float og = __builtin_amdgcn_rcpf(1.f + __expf(-po));
                float ng = 1.f - 2.f * __builtin_amdgcn_rcpf(__expf(2.f * pn) + 1.f);
                float cn = fg * cv + ig * ng;
                float tc = 1.f - 2.f * __builtin_amdgcn_rcpf(__expf(2.f * cn) + 1.f);
                out[off] = og * tc;
                out[(size_t)8388608 + off] = cn;
            }
        }
    }
}

// ---------------------------------------------------------------------------
extern "C" void kernel_launch(void* const* d_in, const int* in_sizes, int n_in,
                              void* d_out, int out_size, void* d_ws, size_t ws_size,
                              hipStream_t stream)
{
    const float* x      = (const float*)d_in[0];
    const float* h      = (const float*)d_in[1];
    const float* c      = (const float*)d_in[2];
    const float* dia_x  = (const float*)d_in[3];
    const float* dia_h  = (const float*)d_in[4];
    const float* Ux     = (const float*)d_in[5];
    const float* Vx     = (const float*)d_in[6];
    const float* Uh0    = (const float*)d_in[7];
    const float* Vh0    = (const float*)d_in[8];
    const float* Uh1    = (const float*)d_in[9];
    const float* Vh1    = (const float*)d_in[10];
    const float* bias_x = (const float*)d_in[11];
    const float* bias_h = (const float*)d_in[12];
    float* out = (float*)d_out;

    char* ws = (char*)d_ws;
    _Float16* TaW  = (_Float16*)(ws + WS_TA);
    _Float16* TbW  = (_Float16*)(ws + WS_TB);
    _Float16* U1f  = (_Float16*)(ws + WS_U1F);
    _Float16* Uh1f = (_Float16*)(ws + WS_UH1F);
    _Float16* W2f  = (_Float16*)(ws + WS_W2);
    float* cx = (float*)(ws + WS_CX);
    float* ch = (float*)(ws + WS_CH);
    float* bb = (float*)(ws + WS_BB);

    prep_kernel<<<496, 256, 0, stream>>>(Ux, Vx, Uh0, Vh0, Uh1, Vh1,
                                         dia_x, dia_h, bias_x, bias_h,
                                         U1f, Uh1f, W2f, cx, ch, bb);
    s1_kernel<<<dim3(512, 3), 256, 0, stream>>>(x, h, U1f, Uh1f, TaW, TbW);
    s2_kernel<<<dim3(256, 8), 256, 0, stream>>>(TaW, TbW, W2f, cx, ch, bb,
                                                x, h, c, out);
}